// Round 1
// baseline (845.409 us; speedup 1.0000x reference)
//
#include <hip/hip_runtime.h>
#include <math.h>

typedef unsigned short u16;
typedef __attribute__((ext_vector_type(8))) short short8;
typedef __attribute__((ext_vector_type(4))) float floatx4;
typedef __attribute__((ext_vector_type(4))) unsigned short ushort4v;

#define DEV static __device__ __forceinline__

DEV u16 f2b(float f) {
  unsigned u = __builtin_bit_cast(unsigned, f);
  u += 0x7fffu + ((u >> 16) & 1u);
  return (u16)(u >> 16);
}
DEV float b2f(u16 h) { return __builtin_bit_cast(float, ((unsigned)h) << 16); }

DEV void gld16(const u16* g, u16* l) {
  __builtin_amdgcn_global_load_lds((__attribute__((address_space(1))) void*)(g),
                                   (__attribute__((address_space(3))) void*)(l), 16, 0, 0);
}

// ---------------- K1: token-shift mixes -> 6 bf16 tensors ----------------
__global__ __launch_bounds__(256) void ew_mix(
    const float* __restrict__ x,
    const float* __restrict__ cr, const float* __restrict__ ck,
    const float* __restrict__ cv, const float* __restrict__ cw,
    const float* __restrict__ ca, const float* __restrict__ cg,
    u16* __restrict__ oxr, u16* __restrict__ oxk, u16* __restrict__ oxv,
    u16* __restrict__ oxw, u16* __restrict__ oxa, u16* __restrict__ oxg)
{
  const long idx = (long)blockIdx.x * 256 + threadIdx.x;  // over 8192*512
  const long row = idx >> 9;
  const int c4 = (int)(idx & 511) << 2;
  const long off = (row << 11) + c4;
  const float4 xc = *(const float4*)(x + off);
  float4 xp = make_float4(0.f, 0.f, 0.f, 0.f);
  if ((row & 4095) != 0) xp = *(const float4*)(x + off - 2048);   // T=4096 per batch
  const float xx0 = xp.x - xc.x, xx1 = xp.y - xc.y, xx2 = xp.z - xc.z, xx3 = xp.w - xc.w;
#define EMIT(cp, op) { const float4 cf = *(const float4*)(cp + c4);            \
    ushort4v o = { f2b(xc.x + xx0*cf.x), f2b(xc.y + xx1*cf.y),                 \
                   f2b(xc.z + xx2*cf.z), f2b(xc.w + xx3*cf.w) };               \
    *(ushort4v*)(op + off) = o; }
  EMIT(cr, oxr); EMIT(ck, oxk); EMIT(cv, oxv);
  EMIT(cw, oxw); EMIT(ca, oxa); EMIT(cg, oxg);
#undef EMIT
}

// ---------------- K2: cast 4 big square weights f32 -> bf16 ----------------
__global__ __launch_bounds__(256) void cast_w4(
    const float* __restrict__ s0, const float* __restrict__ s1,
    const float* __restrict__ s2, const float* __restrict__ s3,
    u16* __restrict__ d0, u16* __restrict__ d1, u16* __restrict__ d2, u16* __restrict__ d3)
{
  const float* s; u16* d;
  switch (blockIdx.y) {
    case 0: s = s0; d = d0; break;
    case 1: s = s1; d = d1; break;
    case 2: s = s2; d = d2; break;
    default: s = s3; d = d3; break;
  }
  const long i = ((long)blockIdx.x * 256 + threadIdx.x) * 8;  // 2048*2048/8 -> 2048 blocks
  const float4 a = *(const float4*)(s + i);
  const float4 b = *(const float4*)(s + i + 4);
  ushort4v lo = { f2b(a.x), f2b(a.y), f2b(a.z), f2b(a.w) };
  ushort4v hi = { f2b(b.x), f2b(b.y), f2b(b.z), f2b(b.w) };
  *(ushort4v*)(d + i) = lo;
  *(ushort4v*)(d + i + 4) = hi;
}

// ---------------- K3: transpose (+zero-pad) LoRA weights -> bf16 [N][K] ----------------
struct TJobs {
  const float* src[8]; u16* dst[8];
  int src_k[8], src_n[8], dst_n[8], dst_k[8];
};
__global__ __launch_bounds__(256) void transpose_small(TJobs j)
{
  const int w = blockIdx.y;
  const long idx = (long)blockIdx.x * 256 + threadIdx.x;
  const long total = (long)j.dst_n[w] * j.dst_k[w];
  if (idx >= total) return;
  const int dk = j.dst_k[w];
  const int n = (int)(idx / dk), k = (int)(idx % dk);
  float v = 0.f;
  if (k < j.src_k[w] && n < j.src_n[w]) v = j.src[w][(long)k * j.src_n[w] + n];
  j.dst[w][idx] = f2b(v);
}

// ---------------- GEMM: C[M,N] = A[M,K](bf16) @ B[N,K](bf16)^T ----------------
// 128x128 tile, BK=64, 4 waves (2x2 of 64x64), mfma 16x16x32 bf16.
// global_load_lds w=16, linear LDS dest; XOR chunk-swizzle applied on global src
// and on the ds_read side (same involution) -> conflict-free reads.
// OP: 0=f32  1=bf16  2=tanh->bf16  3=sigmoid->bf16
//     4=f32 w-transform(+bias) 5=f32 sigmoid(+bias) 6=bf16 sigmoid(+bias)
template<int OP>
__global__ __launch_bounds__(256, 2) void gemm_bt(
    const u16* __restrict__ A, const u16* __restrict__ B,
    void* __restrict__ Cv, const float* __restrict__ bias, int N, int K)
{
  __shared__ __align__(16) u16 sA[128 * 64];
  __shared__ __align__(16) u16 sB[128 * 64];
  const int tid = threadIdx.x;
  const int wave = tid >> 6, lane = tid & 63;
  const int lrow = lane & 15, lkg = lane >> 4;
  const int wm = wave >> 1, wn = wave & 1;
  const int nbn = N >> 7;
  const int bm = blockIdx.x / nbn, bn = blockIdx.x % nbn;

  const u16* Abase = A + (long)bm * 128 * K;
  const u16* Bbase = B + (long)bn * 128 * K;

  floatx4 acc[4][4];
#pragma unroll
  for (int i = 0; i < 4; ++i)
#pragma unroll
    for (int j = 0; j < 4; ++j) acc[i][j] = (floatx4)0.f;

  const int nK = K >> 6;
  for (int kt = 0; kt < nK; ++kt) {
    const int k0 = kt << 6;
    __syncthreads();  // previous tile's reads complete
#pragma unroll
    for (int i = 0; i < 4; ++i) {
      const int c = i * 256 + tid;          // 16B chunk id, 0..1023
      const int row = c >> 3;               // 8 chunks per 64-elem row
      const int sch = (c & 7) ^ (row & 7);  // inverse swizzle on source
      const long goff = (long)row * K + k0 + sch * 8;
      const int lbase = (i * 256 + wave * 64) * 8;  // wave-uniform, lane*16B implicit
      gld16(Abase + goff, &sA[lbase]);
      gld16(Bbase + goff, &sB[lbase]);
    }
    asm volatile("s_waitcnt vmcnt(0)" ::: "memory");
    __syncthreads();
#pragma unroll
    for (int ks = 0; ks < 2; ++ks) {
      short8 af[4], bfr[4];
#pragma unroll
      for (int mi = 0; mi < 4; ++mi) {
        const int row = wm * 64 + mi * 16 + lrow;
        const int ch = (ks * 4 + lkg) ^ (row & 7);
        af[mi] = *(const short8*)&sA[row * 64 + ch * 8];
      }
#pragma unroll
      for (int ni = 0; ni < 4; ++ni) {
        const int row = wn * 64 + ni * 16 + lrow;
        const int ch = (ks * 4 + lkg) ^ (row & 7);
        bfr[ni] = *(const short8*)&sB[row * 64 + ch * 8];
      }
#pragma unroll
      for (int mi = 0; mi < 4; ++mi)
#pragma unroll
        for (int ni = 0; ni < 4; ++ni)
          acc[mi][ni] = __builtin_amdgcn_mfma_f32_16x16x32_bf16(af[mi], bfr[ni], acc[mi][ni], 0, 0, 0);
    }
  }

  // epilogue: C row = (lane>>4)*4 + reg, col = lane&15  [guide §3, m89-verified]
  const int row0 = bm * 128 + wm * 64 + lkg * 4;
  const int col0 = bn * 128 + wn * 64 + lrow;
#pragma unroll
  for (int mi = 0; mi < 4; ++mi) {
#pragma unroll
    for (int ni = 0; ni < 4; ++ni) {
      const int col = col0 + ni * 16;
#pragma unroll
      for (int r = 0; r < 4; ++r) {
        const long o = (long)(row0 + mi * 16 + r) * N + col;
        const float v = acc[mi][ni][r];
        if constexpr (OP == 0) ((float*)Cv)[o] = v;
        else if constexpr (OP == 1) ((u16*)Cv)[o] = f2b(v);
        else if constexpr (OP == 2) ((u16*)Cv)[o] = f2b(tanhf(v));
        else if constexpr (OP == 3) ((u16*)Cv)[o] = f2b(1.f / (1.f + expf(-v)));
        else if constexpr (OP == 4) {
          const float zz = -(v + bias[col]);
          const float sp = fmaxf(zz, 0.f) + log1pf(expf(-fabsf(zz)));
          ((float*)Cv)[o] = -sp - 0.5f;
        } else if constexpr (OP == 5) {
          ((float*)Cv)[o] = 1.f / (1.f + expf(-(v + bias[col])));
        } else if constexpr (OP == 6) {
          ((u16*)Cv)[o] = f2b(1.f / (1.f + expf(-(v + bias[col]))));
        }
      }
    }
  }
}

// ---------------- K6: per-head fused epilogue ----------------
DEV float wsum64(float v) {
  v += __shfl_xor(v, 1);  v += __shfl_xor(v, 2);  v += __shfl_xor(v, 4);
  v += __shfl_xor(v, 8);  v += __shfl_xor(v, 16); v += __shfl_xor(v, 32);
  return v;
}

__global__ __launch_bounds__(256) void ew_head(
    const float* __restrict__ rbuf,    // r  (f32, d_out out-section)
    float* __restrict__ kkbuf,         // in: k0 (f32, d_out kk-section); out: kk
    const float* __restrict__ abuf,    // a  (f32, d_out a-section)
    const u16* __restrict__ v0buf, const u16* __restrict__ vsbuf,
    const u16* __restrict__ gbuf,
    const float* __restrict__ y, const float* __restrict__ vfirst,
    const float* __restrict__ kkc, const float* __restrict__ kac,
    const float* __restrict__ rk, const float* __restrict__ lng,
    const float* __restrict__ lnb, u16* __restrict__ z)
{
  const int tid = threadIdx.x;
  const int wave = tid >> 6, lane = tid & 63;
  const long gh = (long)blockIdx.x * 4 + wave;   // (token,head) id
  const long m = gh >> 5;
  const int h = (int)(gh & 31);
  const int c = h * 64 + lane;
  const long off = (m << 11) + c;

  const float k0 = kkbuf[off];
  const float av = abuf[off];
  const float kf = k0 * (1.f + (av - 1.f) * kac[c]);
  const float kkr = k0 * kkc[c];
  const float nrm = sqrtf(wsum64(kkr * kkr));
  kkbuf[off] = kkr / fmaxf(nrm, 1e-12f);

  const float yv = y[off];
  const float mu = wsum64(yv) * 0.015625f;
  const float dy = yv - mu;
  const float var = wsum64(dy * dy) * 0.015625f;
  const float yn = dy * rsqrtf(var + 0.00064f) * lng[c] + lnb[c];

  const float dot = wsum64(rbuf[off] * kf * rk[c]);

  const float v0v = b2f(v0buf[off]);
  const float sv = b2f(vsbuf[off]);
  const float vv = v0v + (vfirst[off] - v0v) * sv;

  const float y2 = yn + dot * vv;
  z[off] = f2b(y2 * b2f(gbuf[off]));
}

// ---------------- launch ----------------
extern "C" void kernel_launch(void* const* d_in, const int* in_sizes, int n_in,
                              void* d_out, int out_size, void* d_ws, size_t ws_size,
                              hipStream_t stream)
{
  (void)in_sizes; (void)out_size;
  if (n_in < 29) return;
  const int Mrows = 8192;     // B*T
  const long C = 2048;
  const long MB_ = (long)Mrows * C;

  const float* x   = (const float*)d_in[0];
  const float* vf  = (const float*)d_in[1];
  const float* y   = (const float*)d_in[2];
  const float* x_r = (const float*)d_in[3];
  const float* x_w = (const float*)d_in[4];
  const float* x_k = (const float*)d_in[5];
  const float* x_v = (const float*)d_in[6];
  const float* x_a = (const float*)d_in[7];
  const float* x_g = (const float*)d_in[8];
  const float* w0  = (const float*)d_in[9];
  const float* w1  = (const float*)d_in[10];
  const float* w2  = (const float*)d_in[11];
  const float* a0  = (const float*)d_in[12];
  const float* a1  = (const float*)d_in[13];
  const float* a2  = (const float*)d_in[14];
  const float* v0  = (const float*)d_in[15];
  const float* v1  = (const float*)d_in[16];
  const float* v2  = (const float*)d_in[17];
  const float* g1  = (const float*)d_in[18];
  const float* g2  = (const float*)d_in[19];
  const float* k_k = (const float*)d_in[20];
  const float* k_a = (const float*)d_in[21];
  const float* r_k = (const float*)d_in[22];
  const float* W_r = (const float*)d_in[23];
  const float* W_k = (const float*)d_in[24];
  const float* W_v = (const float*)d_in[25];
  const float* W_o = (const float*)d_in[26];
  const float* lng = (const float*)d_in[27];
  const float* lnb = (const float*)d_in[28];

  float* out_sec = (float*)d_out;        // r lives here until final GEMM overwrites
  float* w_sec   = out_sec + MB_;
  float* a_sec   = w_sec + MB_;
  float* kk_sec  = a_sec + MB_;          // k0 lives here; ew_head rewrites in place

  // big W bf16 casts for r/k/v live in the (not-yet-written) w-section of d_out
  u16* Wr16 = (u16*)w_sec;
  u16* Wk16 = Wr16 + C * C;
  u16* Wv16 = Wk16 + C * C;

  u16* p = (u16*)d_ws;
  u16* xr = p;            p += MB_;   // slot0: later v0buf
  u16* xk = p;            p += MB_;   // slot1: later z
  u16* xv = p;            p += MB_;
  u16* xw = p;            p += MB_;   // slot3: later vs
  u16* xa = p;            p += MB_;   // slot4: later g
  u16* xg = p;            p += MB_;
  u16* Wo16 = p;          p += C * C;
  u16* w1T = p;           p += 128 * C;   // [128][2048]
  u16* a1T = p;           p += 128 * C;
  u16* v1T = p;           p += 128 * C;   // rows 64.. zero-padded
  u16* g1T = p;           p += 256 * C;   // rows 224.. zero-padded
  u16* w2T = p;           p += C * 128;   // [2048][128]
  u16* a2T = p;           p += C * 128;
  u16* v2T = p;           p += C * 128;   // cols 64.. zero-padded
  u16* g2T = p;           p += C * 256;   // cols 224.. zero-padded
  u16* hw  = p;           p += (long)Mrows * 128;
  u16* ha  = p;           p += (long)Mrows * 128;
  u16* hv  = p;           p += (long)Mrows * 128;
  u16* hg  = p;           p += (long)Mrows * 256;
  const size_t need = (size_t)((char*)p - (char*)d_ws);
  if (ws_size < need) return;   // fail visibly rather than corrupt

  u16* v0buf = xr;   // aliases: safe by launch order
  u16* zbuf  = xk;
  u16* vsbuf = xw;
  u16* gbuf  = xa;

  // K1: mixes
  ew_mix<<<16384, 256, 0, stream>>>(x, x_r, x_k, x_v, x_w, x_a, x_g,
                                    xr, xk, xv, xw, xa, xg);
  // K2: big weight casts
  cast_w4<<<dim3(2048, 4), 256, 0, stream>>>(W_r, W_k, W_v, W_o, Wr16, Wk16, Wv16, Wo16);
  // K3: LoRA weight transposes (+zero pad)
  TJobs tj;
  {
    const float* s_[8] = { w1, a1, v1, g1, w2, a2, v2, g2 };
    u16* d_[8]         = { w1T, a1T, v1T, g1T, w2T, a2T, v2T, g2T };
    const int sk_[8]   = { 2048, 2048, 2048, 2048, 128, 128, 64, 224 };
    const int sn_[8]   = { 128, 128, 64, 224, 2048, 2048, 2048, 2048 };
    const int dn_[8]   = { 128, 128, 128, 256, 2048, 2048, 2048, 2048 };
    const int dk_[8]   = { 2048, 2048, 2048, 2048, 128, 128, 128, 256 };
    for (int i = 0; i < 8; ++i) {
      tj.src[i] = s_[i]; tj.dst[i] = d_[i];
      tj.src_k[i] = sk_[i]; tj.src_n[i] = sn_[i];
      tj.dst_n[i] = dn_[i]; tj.dst_k[i] = dk_[i];
    }
  }
  transpose_small<<<dim3(2048, 8), 256, 0, stream>>>(tj);

  // LoRA stage-1
  gemm_bt<2><<<64,  256, 0, stream>>>(xw, w1T, hw, nullptr, 128, 2048);   // tanh
  gemm_bt<1><<<64,  256, 0, stream>>>(xa, a1T, ha, nullptr, 128, 2048);
  gemm_bt<1><<<64,  256, 0, stream>>>(xv, v1T, hv, nullptr, 128, 2048);
  gemm_bt<3><<<128, 256, 0, stream>>>(xg, g1T, hg, nullptr, 256, 2048);   // sigmoid
  // big projections
  gemm_bt<0><<<1024, 256, 0, stream>>>(xr, Wr16, out_sec, nullptr, 2048, 2048);  // r
  gemm_bt<0><<<1024, 256, 0, stream>>>(xk, Wk16, kk_sec,  nullptr, 2048, 2048);  // k0
  gemm_bt<1><<<1024, 256, 0, stream>>>(xv, Wv16, v0buf,   nullptr, 2048, 2048);  // v (pre-mix)
  // LoRA stage-2 (+fused epilogues)
  gemm_bt<4><<<1024, 256, 0, stream>>>(hw, w2T, w_sec, w0, 2048, 128);   // w out
  gemm_bt<5><<<1024, 256, 0, stream>>>(ha, a2T, a_sec, a0, 2048, 128);   // a out
  gemm_bt<6><<<1024, 256, 0, stream>>>(hv, v2T, vsbuf, v0, 2048, 128);   // sigmoid mix gate
  gemm_bt<1><<<1024, 256, 0, stream>>>(hg, g2T, gbuf, nullptr, 2048, 256);  // g
  // fused per-head epilogue -> kk (in place) + z
  ew_head<<<65536, 256, 0, stream>>>(out_sec, kk_sec, a_sec, v0buf, vsbuf, gbuf,
                                     y, vf, k_k, k_a, r_k, lng, lnb, zbuf);
  // final projection
  gemm_bt<0><<<1024, 256, 0, stream>>>(zbuf, Wo16, out_sec, nullptr, 2048, 2048);
}